// Round 7
// baseline (444.746 us; speedup 1.0000x reference)
//
#include <hip/hip_runtime.h>
#include <hip/hip_fp16.h>

// Node_Embedding: HeteroGraphConv(sum) of 4 GraphConv relations + PReLU.
// Split design: (1) k_gather — latency-optimized edge gather writing fp16
// agg[2*NB][256] in-place into d_out; (2) k_gemm — dense MFMA f16 GEMM
// [100K,256]@[256,128] + bias + PReLU, in-place over d_out.

#define NB 50000   // nodes per type
#define EB 500000  // edges per relation
#define D  128
#define NCH 98     // ceil(NB/512)
#define DEGBLK 1954  // ceil(EB/256)
#define CVTBLK 3125  // 12500 cvt blocks / 4 (one share per blockIdx.y)
#define CAP 512      // LDS edge-window capacity per relation (mean 160)

struct EdgePtrs { const int* src[4]; const int* dst[4]; };

typedef _Float16 f16x8 __attribute__((ext_vector_type(8)));
typedef float f32x4 __attribute__((ext_vector_type(4)));

__device__ inline float hlo(unsigned u) {
    return __half2float(__ushort_as_half((unsigned short)(u & 0xffffu)));
}
__device__ inline float hhi(unsigned u) {
    return __half2float(__ushort_as_half((unsigned short)(u >> 16)));
}

// Fused: per-relation degree histograms (rank captured) + x -> fp16 convert.
__global__ __launch_bounds__(256) void k_deg_cvt(
    EdgePtrs ep, int* __restrict__ cntout, int* __restrict__ cntin,
    int* __restrict__ rank,
    const float* __restrict__ xd, const float* __restrict__ xs,
    unsigned short* __restrict__ xh) {
    int bx = blockIdx.x, r = blockIdx.y, tid = threadIdx.x;
    if (bx < DEGBLK) {
        int e = bx * 256 + tid;
        if (e < EB) {
            int s = ep.src[r][e], d = ep.dst[r][e];
            atomicAdd(&cntout[r * NB + s], 1);
            rank[(size_t)r * EB + e] = atomicAdd(&cntin[r * NB + d], 1);
        }
    } else {
        int c = (bx - DEGBLK) + CVTBLK * r;       // 0..12499
        if (c < 2 * NB * D / 1024) {
            int i = c * 256 + tid;                 // float4 index
            const int half = NB * D / 4;
            const float* src = (i < half) ? xd : xs;
            int j = (i < half) ? i : i - half;
            float4 v = reinterpret_cast<const float4*>(src)[j];
            ushort4 o;
            o.x = __half_as_ushort(__float2half(v.x));
            o.y = __half_as_ushort(__float2half(v.y));
            o.z = __half_as_ushort(__float2half(v.z));
            o.w = __half_as_ushort(__float2half(v.w));
            reinterpret_cast<ushort4*>(xh)[i] = o;
        }
    }
}

// Pack W (fp32 [4][128][128]) into MFMA B-fragment order, fp16:
// Wb[t][jt][ks][lane][8]: col = jt*16+(lane&15), k = ks*32+(lane>>4)*8+m,
// Wcat_t[k][col] = W[k<128 ? t : 2+t][k&127][col].
__global__ __launch_bounds__(256) void k_wpack(const float* __restrict__ W,
                                               _Float16* __restrict__ Wb) {
    int idx = blockIdx.x * 256 + threadIdx.x;   // 8192 total
    int t = idx >> 12, jt = (idx >> 9) & 7, ks = (idx >> 6) & 7, l = idx & 63;
    int col = jt * 16 + (l & 15);
    int kb = ks * 32 + (l >> 4) * 8;
    _Float16 h[8];
#pragma unroll
    for (int m = 0; m < 8; ++m) {
        int k = kb + m;
        int r = (k < 128) ? t : (2 + t);
        h[m] = (_Float16)W[r * D * D + (k & 127) * D + col];
    }
    *reinterpret_cast<f16x8*>(Wb + (size_t)idx * 8) = *reinterpret_cast<f16x8*>(h);
}

// Phase 1: per-chunk (512 nodes) exclusive scan of in-degrees.
__global__ __launch_bounds__(512) void k_scan1(const int* __restrict__ cntin,
                                               int* __restrict__ offs,
                                               int* __restrict__ chunksum) {
    int r = blockIdx.y, c = blockIdx.x, t = threadIdx.x;
    int node = c * 512 + t;
    int v = (node < NB) ? cntin[r * NB + node] : 0;
    __shared__ int sh[512];
    sh[t] = v;
    __syncthreads();
    for (int off = 1; off < 512; off <<= 1) {
        int u = (t >= off) ? sh[t - off] : 0;
        __syncthreads();
        sh[t] += u;
        __syncthreads();
    }
    int incl = sh[t];
    if (node < NB) offs[r * (NB + 1) + node] = incl - v;  // local exclusive
    if (t == 511) chunksum[r * NCH + c] = incl;
}

// Phase 2: exclusive scan of the NCH chunk totals per relation (wave r).
__global__ __launch_bounds__(256) void k_scan2(int* __restrict__ chunksum) {
    int r = threadIdx.x >> 6, lane = threadIdx.x & 63;
    int* cs = chunksum + r * NCH;
    int s0 = cs[lane];
    int s1 = (64 + lane < NCH) ? cs[64 + lane] : 0;
    int x = s0;
    for (int d = 1; d < 64; d <<= 1) { int u = __shfl_up(x, d, 64); if (lane >= d) x += u; }
    int tot0 = __shfl(x, 63, 64);
    int y = s1;
    for (int d = 1; d < 64; d <<= 1) { int u = __shfl_up(y, d, 64); if (lane >= d) y += u; }
    y += tot0;
    cs[lane] = x - s0;
    if (64 + lane < NCH) cs[64 + lane] = y - s1;
}

// Phase 3: add chunk base; offs[NB] = EB.
__global__ __launch_bounds__(512) void k_scan3(int* __restrict__ offs,
                                               const int* __restrict__ chunksum) {
    int r = blockIdx.y, c = blockIdx.x, t = threadIdx.x;
    int node = c * 512 + t;
    if (node < NB)
        offs[r * (NB + 1) + node] += chunksum[r * NCH + c];
    if (c == NCH - 1 && t == 0) offs[r * (NB + 1) + NB] = EB;
}

// Scatter edges into CSR order via precomputed rank (no atomics).
__global__ __launch_bounds__(256) void k_fill(EdgePtrs ep, const int* __restrict__ cntout,
                                              const int* __restrict__ offs,
                                              const int* __restrict__ rank,
                                              int2* __restrict__ epack) {
    int e = blockIdx.x * blockDim.x + threadIdx.x;
    int r = blockIdx.y;
    if (e < EB) {
        int s = ep.src[r][e], d = ep.dst[r][e];
        int c = cntout[r * NB + s];
        float coef = rsqrtf((float)(c > 1 ? c : 1));
        int pos = offs[r * (NB + 1) + d] + rank[(size_t)r * EB + e];
        epack[(size_t)r * EB + pos] = make_int2(s, __float_as_int(coef));
    }
}

#define PREF(ii, c0, c1, c2, c3, r0, r1, r2, r3)                               \
    {                                                                          \
        int j1 = (ii) + 1 < ghi ? (ii) + 1 : ghi - 1;                          \
        int j2 = (ii) + 2 < ghi ? (ii) + 2 : ghi - 1;                          \
        int j3 = (ii) + 3 < ghi ? (ii) + 3 : ghi - 1;                          \
        int2 q0 = eb[(ii)], q1 = eb[j1], q2 = eb[j2], q3 = eb[j3];             \
        c0 = __int_as_float(q0.y);                                             \
        c1 = ((ii) + 1 < ghi) ? __int_as_float(q1.y) : 0.f;                    \
        c2 = ((ii) + 2 < ghi) ? __int_as_float(q2.y) : 0.f;                    \
        c3 = ((ii) + 3 < ghi) ? __int_as_float(q3.y) : 0.f;                    \
        r0 = *reinterpret_cast<const uint4*>(x + ((unsigned)q0.x * D + cbase));\
        r1 = *reinterpret_cast<const uint4*>(x + ((unsigned)q1.x * D + cbase));\
        r2 = *reinterpret_cast<const uint4*>(x + ((unsigned)q2.x * D + cbase));\
        r3 = *reinterpret_cast<const uint4*>(x + ((unsigned)q3.x * D + cbase));\
    }

#define FMA8(c, r)                                                             \
    {                                                                          \
        acc[0] = fmaf(hlo(r.x), c, acc[0]); acc[1] = fmaf(hhi(r.x), c, acc[1]);\
        acc[2] = fmaf(hlo(r.y), c, acc[2]); acc[3] = fmaf(hhi(r.y), c, acc[3]);\
        acc[4] = fmaf(hlo(r.z), c, acc[4]); acc[5] = fmaf(hhi(r.z), c, acc[5]);\
        acc[6] = fmaf(hlo(r.w), c, acc[6]); acc[7] = fmaf(hhi(r.w), c, acc[7]);\
    }

// Pure gather: 16 rows/block, 16-lane groups, pipelined; writes fp16 agg
// (cols 0-127 rel A, 128-255 rel B) in-place into d_out.
__global__ __launch_bounds__(256, 6) void k_gather(
    const unsigned short* __restrict__ xh,  // [2][NB][D] fp16: drug then dis
    const int* __restrict__ offs, const int2* __restrict__ epack,
    unsigned short* __restrict__ agg) {     // [2*NB][256] fp16 (aliases d_out)
    __shared__ int2 ebuf[2][CAP];
    __shared__ int soff[2][17];
    const int t = blockIdx.y;
    const int row0 = blockIdx.x * 16;
    const int tid = threadIdx.x;
    const int g = tid >> 4, l16 = tid & 15;
    const int cbase = l16 * 8;          // this lane's 8 fp16 columns

    if (tid < 34) {
        int h = tid / 17, k = tid % 17;
        int rel = h ? (2 + t) : t;
        soff[h][k] = offs[rel * (NB + 1) + row0 + k];
    }
    __syncthreads();

    // stage both relations' edge windows (first CAP each)
    for (int h = 0; h < 2; ++h) {
        int rel = h ? (2 + t) : t;
        const int2* epk = epack + (size_t)rel * EB;
        int base = soff[h][0];
        int tot = soff[h][16] - base; if (tot > CAP) tot = CAP;
        for (int i = tid; i < tot; i += 256) ebuf[h][i] = epk[base + i];
    }
    __syncthreads();

    for (int h = 0; h < 2; ++h) {
        int rel = h ? (2 + t) : t;
        const unsigned short* x = xh + (size_t)h * NB * D;
        const int2* epk = epack + (size_t)rel * EB;
        const int base = soff[h][0];
        const int glo = soff[h][g] - base;
        const int ghi0 = soff[h][g + 1] - base;
        const int ghi = ghi0 < CAP ? ghi0 : CAP;   // LDS-resident part
        const int2* eb = ebuf[h];
        float acc[8] = {0.f, 0.f, 0.f, 0.f, 0.f, 0.f, 0.f, 0.f};

        if (glo < ghi) {
            uint4 rA0, rA1, rA2, rA3, rB0, rB1, rB2, rB3;
            float cA0, cA1, cA2, cA3, cB0, cB1, cB2, cB3;
            PREF(glo, cA0, cA1, cA2, cA3, rA0, rA1, rA2, rA3);
            for (int i = glo; i < ghi; i += 8) {
                bool hasB = (i + 4 < ghi);
                if (hasB) PREF(i + 4, cB0, cB1, cB2, cB3, rB0, rB1, rB2, rB3);
                FMA8(cA0, rA0); FMA8(cA1, rA1); FMA8(cA2, rA2); FMA8(cA3, rA3);
                if (i + 8 < ghi) PREF(i + 8, cA0, cA1, cA2, cA3, rA0, rA1, rA2, rA3);
                if (hasB) { FMA8(cB0, rB0); FMA8(cB1, rB1); FMA8(cB2, rB2); FMA8(cB3, rB3); }
            }
        }
        // rare overflow tail straight from global
        for (int i = (glo > CAP ? glo : CAP); i < ghi0; ++i) {
            int2 p = epk[base + i];
            float cc = __int_as_float(p.y);
            uint4 rr = *reinterpret_cast<const uint4*>(x + ((unsigned)p.x * D + cbase));
            FMA8(cc, rr);
        }
        int dg = ghi0 - glo;
        float di = rsqrtf((float)(dg > 1 ? dg : 1));
        unsigned q[4];
#pragma unroll
        for (int k2 = 0; k2 < 4; ++k2) {
            unsigned lo = __half_as_ushort(__float2half(acc[2 * k2] * di));
            unsigned hi = __half_as_ushort(__float2half(acc[2 * k2 + 1] * di));
            q[k2] = lo | (hi << 16);
        }
        *reinterpret_cast<uint4*>(
            agg + ((size_t)(t * NB + row0 + g) * 256 + h * 128 + cbase)) =
            make_uint4(q[0], q[1], q[2], q[3]);
    }
}

// Dense MFMA GEMM: out[r][j] = prelu(sum_k agg[r][k] * Wcat_t[k][j] + bias).
// 64 rows/block (wave w: 16 rows), 128 cols, K=256. In-place over d_out
// (each wave reads exactly the rows it writes; loads complete before stores).
__global__ __launch_bounds__(256) void k_gemm(
    const _Float16* agg,                    // aliases out
    const _Float16* __restrict__ Wb,
    const float* __restrict__ b, const float* __restrict__ prelu_a,
    float* out) {
    const int t = blockIdx.y;
    const int tid = threadIdx.x, w = tid >> 6, l = tid & 63;
    const int rbase = t * NB + blockIdx.x * 64 + w * 16;
    const int rmax = t * NB + NB - 1;
    const int lk = (l >> 4) * 8;
    f32x4 acc[8] = {};
    const f16x8* wb = reinterpret_cast<const f16x8*>(Wb + (size_t)t * 32768);
    int ra = rbase + (l & 15); if (ra > rmax) ra = rmax;
    const _Float16* ap = agg + (size_t)ra * 256 + lk;
#pragma unroll
    for (int ks = 0; ks < 8; ++ks) {
        f16x8 a = *reinterpret_cast<const f16x8*>(ap + ks * 32);
#pragma unroll
        for (int jt = 0; jt < 8; ++jt) {
            f16x8 bf = wb[(jt * 8 + ks) * 64 + l];
            acc[jt] = __builtin_amdgcn_mfma_f32_16x16x32_f16(a, bf, acc[jt], 0, 0, 0);
        }
    }
    float pa = prelu_a[0];
    const int rowoff = (l >> 4) * 4;
#pragma unroll
    for (int jt = 0; jt < 8; ++jt) {
        int col = jt * 16 + (l & 15);
        float bs = b[t * D + col] + b[(2 + t) * D + col];
#pragma unroll
        for (int m = 0; m < 4; ++m) {
            int grow = rbase + rowoff + m;
            if (grow <= rmax) {
                float v = acc[jt][m] + bs;
                v = v >= 0.f ? v : pa * v;
                out[(size_t)grow * D + col] = v;
            }
        }
    }
}

extern "C" void kernel_launch(void* const* d_in, const int* in_sizes, int n_in,
                              void* d_out, int out_size, void* d_ws, size_t ws_size,
                              hipStream_t stream) {
    const float* x_drug = (const float*)d_in[0];
    const float* x_dis  = (const float*)d_in[1];
    const float* W      = (const float*)d_in[2];   // [4,128,128]
    const float* b      = (const float*)d_in[3];   // [4,128]
    const float* pa     = (const float*)d_in[4];   // [1]
    EdgePtrs ep;
    ep.src[0] = (const int*)d_in[5];  ep.dst[0] = (const int*)d_in[6];   // dd
    ep.src[1] = (const int*)d_in[7];  ep.dst[1] = (const int*)d_in[8];   // ds
    ep.src[2] = (const int*)d_in[9];  ep.dst[2] = (const int*)d_in[10];  // sd
    ep.src[3] = (const int*)d_in[11]; ep.dst[3] = (const int*)d_in[12];  // ss

    // workspace layout (bytes)
    char* ws = (char*)d_ws;
    int*  cntout   = (int*)(ws + 0);         // 4*NB ints
    int*  cntin    = (int*)(ws + 800000);    // 4*NB ints
    int*  offs     = (int*)(ws + 1600000);   // 4*(NB+1) ints
    int*  chunksum = (int*)(ws + 2400064);   // 4*NCH ints
    int*  rank     = (int*)(ws + 2401664);   // 4*EB ints (8 MB)
    int2* epack    = (int2*)(ws + 10401664); // 4*EB int2 (16 MB)
    unsigned short* xh = (unsigned short*)(ws + 26401664); // 2*NB*D fp16 (25.6 MB)
    _Float16* Wb   = (_Float16*)(ws + 52001664); // 128 KB packed W
    // total ~52.1 MB

    hipMemsetAsync(ws, 0, 1600000, stream);  // cntout, cntin

    k_deg_cvt<<<dim3(DEGBLK + CVTBLK, 4), 256, 0, stream>>>(
        ep, cntout, cntin, rank, x_drug, x_dis, xh);
    k_wpack<<<32, 256, 0, stream>>>(W, Wb);
    k_scan1<<<dim3(NCH, 4), 512, 0, stream>>>(cntin, offs, chunksum);
    k_scan2<<<1, 256, 0, stream>>>(chunksum);
    k_scan3<<<dim3(NCH, 4), 512, 0, stream>>>(offs, chunksum);
    k_fill<<<dim3(DEGBLK, 4), 256, 0, stream>>>(ep, cntout, offs, rank, epack);
    k_gather<<<dim3(NB / 16, 2), 256, 0, stream>>>(
        xh, offs, epack, (unsigned short*)d_out);
    k_gemm<<<dim3(782, 2), 256, 0, stream>>>(
        (const _Float16*)d_out, Wb, b, pa, (float*)d_out);
}